// Round 1
// 66.933 us; speedup vs baseline: 1.0062x; 1.0062x over previous
//
#include <hip/hip_runtime.h>
#include <math.h>

// x: (64,1,128,128) f32 -> K=2 conv -> 127x127 patches/image.
// Quantum circuit collapses analytically (CNOTs couple only (0,1),(2,3); Z0
// readout => wires 2,3 trace out; t0=x[i,j], t1=x[i,j+1]):
//   q = k0 + k1 cos t0 + k2 cos t1 + k3 cos t0 cos t1 + k4 sin t0 sin t1
//
// R9 structure (fused single dispatch):
//  * Timed-region analysis: 40.7us of the 67us is the harness's 256MiB
//    workspace poison fill (inside the graph, untouchable). Addressable
//    budget ~26us = row_kernel + final_kernel + graph gaps.
//  * Fusion WITHOUT cross-block sync (R5 spin=+50us, R6 counter RMW=+45us):
//    one block per image (64 blocks x 1024 threads, 4 row-passes/thread),
//    block-internal reduction, out[img] written directly. final_kernel and
//    the part[] workspace are gone entirely.
//  * All global loads + all sincos/shfl issued BEFORE the barrier; tid0's
//    ~500-cycle circuit_coeffs chain hides under that latency.
//  * float4 loads; quantum term needs each patch's top row => one sincos
//    per element, neighbor cos/sin via __shfl_down; conv = position-weighted
//    single pass.

#define XW 128
#define NP (127 * 127)
#define NB 64
#define BLK 1024

__device__ __forceinline__ void circuit_coeffs(const float* __restrict__ ry,
                                               float k[5]) {
    float U[4][4] = {{1,0,0,0},{0,1,0,0},{0,0,1,0},{0,0,0,1}};
    for (int l = 0; l < 2; ++l) {
        float s0, c0, s1, c1;
        __sincosf(0.5f * ry[l*4+0], &s0, &c0);
        __sincosf(0.5f * ry[l*4+1], &s1, &c1);
        for (int q1 = 0; q1 < 2; ++q1)
            for (int c = 0; c < 4; ++c) {
                float a = U[q1][c], d = U[2+q1][c];
                U[q1][c]   = c0*a - s0*d;
                U[2+q1][c] = s0*a + c0*d;
            }
        for (int m = 0; m < 2; ++m)
            for (int c = 0; c < 4; ++c) {
                float a = U[2*m][c], d = U[2*m+1][c];
                U[2*m][c]   = c1*a - s1*d;
                U[2*m+1][c] = s1*a + c1*d;
            }
        for (int c = 0; c < 4; ++c) { float t = U[2][c]; U[2][c] = U[3][c]; U[3][c] = t; }
    }
    float pA=0, pB=0, pC=0, pD=0, pAD=0, pBC=0;
    for (int r = 0; r < 4; ++r) {
        float g = (r < 2) ? 1.f : -1.f;
        pA  += g * U[r][0] * U[r][0];
        pB  += g * U[r][1] * U[r][1];
        pC  += g * U[r][2] * U[r][2];
        pD  += g * U[r][3] * U[r][3];
        pAD += g * U[r][0] * U[r][3];
        pBC += g * U[r][1] * U[r][2];
    }
    k[0] = 0.25f * (pA + pB + pC + pD);
    k[1] = 0.25f * (pA + pB - pC - pD);
    k[2] = 0.25f * (pA - pB + pC - pD);
    k[3] = 0.25f * (pA - pB - pC + pD);
    k[4] = 0.50f * (pBC - pAD);
}

// One block = one image. 16 waves; wave w covers rows 2w,2w+1 (lanes 0-31 /
// 32-63) in each of 4 passes (row += 32/pass). Lane loads float4 (cols
// 4*(lane&31)..+3).
__global__ __launch_bounds__(BLK) void fused_kernel(
    const float* __restrict__ x,
    const float* __restrict__ conv_w,
    const float* __restrict__ conv_b,
    const float* __restrict__ ry,
    const float* __restrict__ head_w,
    const float* __restrict__ head_b,
    float* __restrict__ out)
{
    __shared__ float sk[5];            // hw1-prescaled k1..k4, cconst
    __shared__ float red[BLK / 64];

    const int tid   = threadIdx.x;
    const int lane  = tid & 63;
    const int wave  = tid >> 6;        // 0..15
    const int half  = lane >> 5;       // 0: first row of pair, 1: second
    const int col0  = (lane & 31) << 2;
    const int img   = blockIdx.x;
    const int rbase = (wave << 1) + half;  // 0..31

    // Issue all global loads first (independent of coeffs).
    const float4* xr = (const float4*)(x + (size_t)img * 128 * XW);
    float4 ee[4];
    #pragma unroll
    for (int p = 0; p < 4; ++p)
        ee[p] = xr[(rbase + (p << 5)) * 32 + (lane & 31)];

    if (tid == 0) {
        float k[5];
        circuit_coeffs(ry, k);
        const float hw1 = head_w[1];
        sk[0] = hw1 * k[1]; sk[1] = hw1 * k[2];
        sk[2] = hw1 * k[3]; sk[3] = hw1 * k[4];
        sk[4] = head_w[0] * conv_b[0] + hw1 * k[0] + head_b[0];
    }

    // All transcendental + cross-lane work before the barrier; none of it
    // depends on sk[]. (Row 127's sincos is computed-but-unused: uniform
    // code, no divergence around the shfl.)
    float cA[4][4], sA[4][4], cN[4], sN[4];
    #pragma unroll
    for (int p = 0; p < 4; ++p) {
        __sincosf(ee[p].x, &sA[p][0], &cA[p][0]);
        __sincosf(ee[p].y, &sA[p][1], &cA[p][1]);
        __sincosf(ee[p].z, &sA[p][2], &cA[p][2]);
        __sincosf(ee[p].w, &sA[p][3], &cA[p][3]);
        cN[p] = __shfl_down(cA[p][0], 1, 64);   // next lane's first cos/sin
        sN[p] = __shfl_down(sA[p][0], 1, 64);
    }

    __syncthreads();

    const float hw0 = head_w[0];
    const float w0 = hw0 * conv_w[0], w1 = hw0 * conv_w[1];
    const float w2 = hw0 * conv_w[2], w3 = hw0 * conv_w[3];
    const float k1 = sk[0], k2 = sk[1], k3 = sk[2], k4 = sk[3];

    float acc = 0.f;
    #pragma unroll
    for (int p = 0; p < 4; ++p) {
        const int row = rbase + (p << 5);      // 0..127
        // conv row factors: elem (row,c) weight = [row<=126]w0+[row>=1]w2
        // (left col) + col-shifted w1/w3 analog
        const float P  = (row < 127 ? w0 : 0.f) + (row > 0 ? w2 : 0.f);
        const float Q  = (row < 127 ? w1 : 0.f) + (row > 0 ? w3 : 0.f);
        const float PQ = P + Q;

        // conv: col c weight = P*(c<=126) + Q*(c>=1)
        acc += ee[p].x * (col0 == 0 ? P : PQ)
             + ee[p].y * PQ
             + ee[p].z * PQ
             + ee[p].w * (col0 == 124 ? Q : PQ);

        if (row < 127) {
            const float c0 = cA[p][0], c1 = cA[p][1];
            const float c2 = cA[p][2], c3 = cA[p][3];
            const float s0 = sA[p][0], s1 = sA[p][1];
            const float s2 = sA[p][2], s3 = sA[p][3];
            acc += k1 * c0 + k2 * c1 + k3 * c0 * c1 + k4 * s0 * s1; // j=col0
            acc += k1 * c1 + k2 * c2 + k3 * c1 * c2 + k4 * s1 * s2; // +1
            acc += k1 * c2 + k2 * c3 + k3 * c2 * c3 + k4 * s2 * s3; // +2
            if (col0 < 124)                                          // +3
                acc += k1 * c3 + k2 * cN[p] + k3 * c3 * cN[p]
                     + k4 * s3 * sN[p];
        }
    }

    // wave reduce -> LDS -> final 16-way reduce in wave 0 -> out[img]
    for (int off = 32; off > 0; off >>= 1)
        acc += __shfl_down(acc, off, 64);
    if (lane == 0) red[wave] = acc;
    __syncthreads();
    if (wave == 0) {
        float v = (lane < BLK / 64) ? red[lane] : 0.f;
        for (int off = 8; off > 0; off >>= 1)
            v += __shfl_down(v, off, 64);
        if (lane == 0) out[img] = v * (1.0f / NP) + sk[4];
    }
}

extern "C" void kernel_launch(void* const* d_in, const int* in_sizes, int n_in,
                              void* d_out, int out_size, void* d_ws, size_t ws_size,
                              hipStream_t stream) {
    const float* x      = (const float*)d_in[0];
    const float* conv_w = (const float*)d_in[1];
    const float* conv_b = (const float*)d_in[2];
    const float* ry     = (const float*)d_in[3];
    const float* head_w = (const float*)d_in[4];
    const float* head_b = (const float*)d_in[5];
    float* out = (float*)d_out;

    fused_kernel<<<dim3(NB), dim3(BLK), 0, stream>>>(
        x, conv_w, conv_b, ry, head_w, head_b, out);
}